// Round 7
// baseline (455.616 us; speedup 1.0000x reference)
//
#include <hip/hip_runtime.h>
#include <math.h>
#include <stdint.h>

#define N_ROWS 131072
#define DIM 64
#define KC 64
#define NBLK 512
#define ROWS_PB 256

typedef __attribute__((ext_vector_type(8))) short short8;
typedef __attribute__((ext_vector_type(8))) unsigned short ushort8;
typedef __attribute__((ext_vector_type(16))) float float16;
typedef __attribute__((ext_vector_type(4))) unsigned int uint4v;
typedef __attribute__((ext_vector_type(2))) unsigned long long ulong2v;

// scratch layout (float offsets into d_out's compressed region [0, 8388608)):
// WT bf16 [64][131072] = 16MB at byte 0; partial [512][64][64] f32 = 8MB;
// suma [512][64]; newC [64][64]; normpart 128 doubles.
// cur lives in the clusters_out region (ob + 8388608, 16KB exact).
// attn region untouched until iter 9; compress overwrites compressed last.
#define PARTIAL_OFF 4194304u
#define SUMA_OFF    6291456u
#define NEWC_OFF    6324224u
#define NORM_BYTE_OFF (6328320ull * 4ull)

// round-to-nearest-even bf16 (unbiased; truncation's random error is ~2x
// larger AND biased -> measured 7e-4 cluster error in r3/r5; RNE passes)
__device__ __forceinline__ uint32_t rne16(float a) {
  uint32_t u = __float_as_uint(a);
  return (u + 0x7fffu + ((u >> 16) & 1u)) >> 16;
}

__device__ __forceinline__ uint32_t pack_bf16(float a, float b) {
  return rne16(a) | (rne16(b) << 16);
}

// RNE split: x = hi + lo + eps, |lo| <= 2^-9|x|, |eps| <= 2^-17|x|, unbiased
__device__ __forceinline__ void split2(float a, float b, uint32_t& hi, uint32_t& lo) {
  uint32_t ha = rne16(a), hb = rne16(b);
  hi = ha | (hb << 16);
  float la = a - __uint_as_float(ha << 16);
  float lb = b - __uint_as_float(hb << 16);
  lo = pack_bf16(la, lb);
}

// prep: WT[d][n] = bf16_rne(W[n][d]) (transposed copy for phase-2 B-frags)
__global__ __launch_bounds__(256) void prep_kernel(const float* __restrict__ W,
                                                   unsigned short* __restrict__ WT) {
  __shared__ unsigned short Tsh[64][256];
  const int t = threadIdx.x;
  const int blk = blockIdx.x;
  const int r = blk * 256 + t;
  const float4* p = (const float4*)(W + (size_t)r * DIM);
#pragma unroll
  for (int c = 0; c < 16; ++c) {
    float4 v = p[c];
    Tsh[c * 4 + 0][t] = (unsigned short)rne16(v.x);
    Tsh[c * 4 + 1][t] = (unsigned short)rne16(v.y);
    Tsh[c * 4 + 2][t] = (unsigned short)rne16(v.z);
    Tsh[c * 4 + 3][t] = (unsigned short)rne16(v.w);
  }
  __syncthreads();
#pragma unroll
  for (int it = 0; it < 8; ++it) {
    const int idx = it * 256 + t;
    const int d = idx >> 5, c8 = (idx & 31) * 8;
    ushort8 v = *(const ushort8*)&Tsh[d][c8];
    *(ushort8*)(WT + (size_t)d * N_ROWS + blk * 256 + c8) = v;
  }
}

// One k-means iteration. 512 blocks x 512 threads (8 waves).
// Phase 1 (swapped): dot = mfma(A=clusters, B=W-rows), load/split/MFMA fused
// per ko-chunk to keep <=8 f32 live (r6 held 32 from kernel top -> spills).
// Register softmax with a single shfl_xor(32) for max and sum.
// Phase 2: U = attnT @ W via mfma(attnT-frag, WT-frag loaded inline); 8 waves
// = 4 output quadrants x 2 k-row halves, combined through LDS.
__global__ __launch_bounds__(512, 4) void dkm_iter(
    const float* __restrict__ W, const unsigned short* __restrict__ WT,
    const float* __restrict__ Cinit,
    const float* __restrict__ newC, float* __restrict__ cur,
    const double* __restrict__ normpart,
    float* __restrict__ partial, float* __restrict__ sumA,
    float* __restrict__ attn_out, int useSel, int writeAttn)
{
  __shared__ __align__(16) short CbfHi[64][68];   // clusters hi bf16 (pad 68)
  __shared__ __align__(16) short CbfLo[64][68];   // clusters lo bf16
  __shared__ __align__(16) short attnT[64][264];  // attn^T bf16 [cl][row], pad
  __shared__ float csqL[64];
  __shared__ float red[512];
  __shared__ int s_cond;

  const int t = threadIdx.x;
  const int blk = blockIdx.x;
  const int wid = t >> 6, lane = t & 63, l31 = lane & 31, lh = lane >> 5;
  const int half = wid >> 2, quad = wid & 3, mg = quad >> 1, ng = quad & 1;
  const int rowBase = blk * ROWS_PB;
  const int myrow = rowBase + wid * 32 + l31;

  // ---- previous-iteration convergence gate (wave 0) ----
  if (wid == 0) {
    double v = useSel ? (normpart[lane] + normpart[64 + lane]) : 0.0;
    v += __shfl_xor(v, 1); v += __shfl_xor(v, 2); v += __shfl_xor(v, 4);
    v += __shfl_xor(v, 8); v += __shfl_xor(v, 16); v += __shfl_xor(v, 32);
    if (lane == 0) s_cond = (v > 1.0e-8) ? 1 : 0;  // ||.||_F > 1e-4
  }
  __syncthreads();  // s_cond ready

  const float* src = useSel ? (s_cond ? newC : cur) : Cinit;

  // ---- stage clusters (RNE split hi/lo), csq via 8-lane shfl, cur write ----
  {
    const int crow = t >> 3, cc = (t & 7) * 8;
    float4 c0 = *(const float4*)(src + crow * 64 + cc);
    float4 c1 = *(const float4*)(src + crow * 64 + cc + 4);
    if (blk == 0) {  // single-block cur update (idempotent when src==cur)
      *(float4*)(cur + crow * 64 + cc) = c0;
      *(float4*)(cur + crow * 64 + cc + 4) = c1;
    }
    uint32_t h0, h1, h2, h3, l0, l1, l2, l3;
    split2(c0.x, c0.y, h0, l0); split2(c0.z, c0.w, h1, l1);
    split2(c1.x, c1.y, h2, l2); split2(c1.z, c1.w, h3, l3);
    uint32_t* ph = (uint32_t*)&CbfHi[crow][cc];
    ph[0] = h0; ph[1] = h1; ph[2] = h2; ph[3] = h3;
    uint32_t* pl = (uint32_t*)&CbfLo[crow][cc];
    pl[0] = l0; pl[1] = l1; pl[2] = l2; pl[3] = l3;
    float sq = c0.x*c0.x + c0.y*c0.y + c0.z*c0.z + c0.w*c0.w
             + c1.x*c1.x + c1.y*c1.y + c1.z*c1.z + c1.w*c1.w;
    sq += __shfl_xor(sq, 1); sq += __shfl_xor(sq, 2); sq += __shfl_xor(sq, 4);
    if ((t & 7) == 0) csqL[crow] = sq;
  }
  __syncthreads();  // CbfHi/CbfLo + csqL ready

  // ---- phase 1: dot = mfma(C, Wrow), fused load+split+MFMA per k-chunk ----
  float16 dot0 = {0,0,0,0, 0,0,0,0, 0,0,0,0, 0,0,0,0};
  float16 dot1 = {0,0,0,0, 0,0,0,0, 0,0,0,0, 0,0,0,0};
  float w2 = 0.f;
  const float* pw = W + (size_t)myrow * 64 + lh * 8;
#pragma unroll
  for (int ko = 0; ko < 4; ++ko) {
    float4 a = *(const float4*)(pw + ko * 16);
    float4 b = *(const float4*)(pw + ko * 16 + 4);
    w2 += a.x*a.x + a.y*a.y + a.z*a.z + a.w*a.w
        + b.x*b.x + b.y*b.y + b.z*b.z + b.w*b.w;
    uint32_t h0, h1, h2, h3, l0, l1, l2, l3;
    split2(a.x, a.y, h0, l0); split2(a.z, a.w, h1, l1);
    split2(b.x, b.y, h2, l2); split2(b.z, b.w, h3, l3);
    uint4v th = {h0, h1, h2, h3};
    uint4v tl = {l0, l1, l2, l3};
    short8 wHi = __builtin_bit_cast(short8, th);
    short8 wLo = __builtin_bit_cast(short8, tl);
#pragma unroll
    for (int nt = 0; nt < 2; ++nt) {
      const unsigned long long* ph = (const unsigned long long*)&CbfHi[nt * 32 + l31][ko * 16 + lh * 8];
      const unsigned long long* pl = (const unsigned long long*)&CbfLo[nt * 32 + l31][ko * 16 + lh * 8];
      ulong2v vh = {ph[0], ph[1]};
      ulong2v vl = {pl[0], pl[1]};
      short8 cHi = __builtin_bit_cast(short8, vh);
      short8 cLo = __builtin_bit_cast(short8, vl);
      float16& dd = nt ? dot1 : dot0;
      dd = __builtin_amdgcn_mfma_f32_32x32x16_bf16(cHi, wHi, dd, 0, 0, 0);
      dd = __builtin_amdgcn_mfma_f32_32x32x16_bf16(cLo, wHi, dd, 0, 0, 0);
      dd = __builtin_amdgcn_mfma_f32_32x32x16_bf16(cHi, wLo, dd, 0, 0, 0);
    }
  }
  w2 += __shfl_xor(w2, 32);

  // ---- register softmax (row l31; lane^32 holds complementary clusters) ----
  float mx = -3.4e38f;
#pragma unroll
  for (int j = 0; j < 16; ++j) {
    const int cl = (j & 3) + 8 * (j >> 2) + 4 * lh;
    float d20 = fmaxf(fmaf(-2.f, dot0[j], w2 + csqL[cl]), 0.f);
    float d21 = fmaxf(fmaf(-2.f, dot1[j], w2 + csqL[cl + 32]), 0.f);
    float g0 = -sqrtf(d20), g1 = -sqrtf(d21);
    dot0[j] = g0; dot1[j] = g1;
    mx = fmaxf(mx, fmaxf(g0, g1));
  }
  mx = fmaxf(mx, __shfl_xor(mx, 32));
  float s = 0.f;
#pragma unroll
  for (int j = 0; j < 16; ++j) {
    float e0 = __expf(dot0[j] - mx), e1 = __expf(dot1[j] - mx);
    dot0[j] = e0; dot1[j] = e1;
    s += e0 + e1;
  }
  s += __shfl_xor(s, 32);
  float inv = __builtin_amdgcn_rcpf(s);

  // ---- attn out (iter 9) + pack attnT bf16 RNE for phase2 A-frags ----
  const int colA = wid * 32 + l31;
#pragma unroll
  for (int j = 0; j < 16; ++j) {
    const int cl = (j & 3) + 8 * (j >> 2) + 4 * lh;
    float a0 = dot0[j] * inv, a1 = dot1[j] * inv;
    if (writeAttn) {
      attn_out[(size_t)myrow * 64 + cl] = a0;
      attn_out[(size_t)myrow * 64 + cl + 32] = a1;
    }
    attnT[cl][colA] = (short)rne16(a0);
    attnT[cl + 32][colA] = (short)rne16(a1);
  }
  __syncthreads();  // attnT complete (dot0/dot1 dead from here)

  // ---- phase 2: U-quadrant (mg,ng), k-row half `half`; B-frags inline ----
  float16 Uacc = {0,0,0,0, 0,0,0,0, 0,0,0,0, 0,0,0,0};
  const int arow = mg * 32 + l31;
  const unsigned short* pwt =
      WT + (size_t)(ng * 32 + l31) * N_ROWS + rowBase + half * 128 + lh * 8;
#pragma unroll
  for (int c2 = 0; c2 < 4; ++c2) {
#pragma unroll
    for (int kc = 0; kc < 2; ++kc) {
      const unsigned long long* pa =
          (const unsigned long long*)&attnT[arow][half * 128 + c2 * 32 + kc * 16 + lh * 8];
      ulong2v va = {pa[0], pa[1]};
      short8 af = __builtin_bit_cast(short8, va);
      ushort8 wv = *(const ushort8*)(pwt + c2 * 32 + kc * 16);
      short8 bf = __builtin_bit_cast(short8, wv);
      Uacc = __builtin_amdgcn_mfma_f32_32x32x16_bf16(af, bf, Uacc, 0, 0, 0);
    }
  }

  // ---- sumA: column sums of attnT (bf16 RNE; denominator matches
  //      numerator's weights -> unbiased, noise ~1e-6 relative) ----
  {
    const int sk = t & 63, sg = t >> 6;
    float ssum = 0.f;
#pragma unroll
    for (int q2 = 0; q2 < 4; ++q2) {
      const uint32_t* pq = (const uint32_t*)&attnT[sk][sg * 32 + q2 * 8];
#pragma unroll
      for (int w = 0; w < 4; ++w) {
        uint32_t dv = pq[w];
        ssum += __uint_as_float(dv << 16) + __uint_as_float(dv & 0xffff0000u);
      }
    }
    red[t] = ssum;
  }
  __syncthreads();  // phase-2 A-reads + sumA reads done; red ready

  float* ured = (float*)&attnT[0][0];  // 16KB overlay on attnT
  if (half == 1) {
#pragma unroll
    for (int j = 0; j < 16; ++j) ured[(quad * 16 + j) * 64 + lane] = Uacc[j];
  }
  if (t < 64) {
    sumA[blk * 64 + t] = ((red[t] + red[t + 64]) + (red[t + 128] + red[t + 192])) +
                         ((red[t + 256] + red[t + 320]) + (red[t + 384] + red[t + 448]));
  }
  __syncthreads();
  if (half == 0) {
#pragma unroll
    for (int j = 0; j < 16; ++j) {
      float u = Uacc[j] + ured[(quad * 16 + j) * 64 + lane];
      const int k = mg * 32 + (j & 3) + 8 * (j >> 2) + 4 * lh;
      partial[((size_t)blk * 64 + k) * 64 + ng * 32 + l31] = u;
    }
  }
}

// Reduce 512 block partials -> newC (f64), norm partials. 128 blocks: (k, dhalf).
__global__ __launch_bounds__(256) void reduce_kernel(
    const float* __restrict__ partial, const float* __restrict__ sumAp,
    const float* __restrict__ curC, float* __restrict__ newC,
    double* __restrict__ normpart) {
  const int k = blockIdx.x >> 1, dh = blockIdx.x & 1;
  const int t = threadIdx.x;
  const int d = dh * 32 + (t & 31), q = t >> 5;
  double acc = 0.0;
  for (int b = q * 64; b < q * 64 + 64; ++b)
    acc += (double)partial[((size_t)b * 64 + k) * 64 + d];
  __shared__ double sh[256];
  __shared__ double sh2[256];
  sh[t] = acc;
  sh2[t] = (double)sumAp[t * 64 + k] + (double)sumAp[(t + 256) * 64 + k];
  __syncthreads();
  for (int s = 128; s >= 1; s >>= 1) {
    if (t < s) sh2[t] += sh2[t + s];
    __syncthreads();
  }
  if (t < 32) {
    double tot = ((sh[t] + sh[t + 32]) + (sh[t + 64] + sh[t + 96])) +
                 ((sh[t + 128] + sh[t + 160]) + (sh[t + 192] + sh[t + 224]));
    float nc = (float)(tot / sh2[0]);
    newC[k * 64 + d] = nc;
    double diff = (double)curC[k * 64 + d] - (double)nc;
    sh[t] = diff * diff;
  }
  __syncthreads();
  if (t == 0) {
    double s = 0.0;
#pragma unroll
    for (int i = 0; i < 32; ++i) s += sh[i];
    normpart[blockIdx.x] = s;
  }
}

// Final select: clusters_out = (||cur9 - new9|| > eps) ? newC : cur
// (cur aliases clusters_out; per-element read-then-write is safe)
__global__ __launch_bounds__(256) void finalize_kernel(
    const double* __restrict__ np, const float* __restrict__ newC,
    const float* __restrict__ cur, float* __restrict__ clusters_out) {
  __shared__ double sh[64];
  __shared__ int sc;
  int t = threadIdx.x;
  if (t < 64) sh[t] = np[t] + np[t + 64];
  __syncthreads();
  if (t == 0) {
    double s = 0.0;
    for (int i = 0; i < 64; ++i) s += sh[i];
    sc = (s > 1.0e-8) ? 1 : 0;
  }
  __syncthreads();
  const float* src = sc ? newC : cur;
  for (int m = t; m < 4096; m += 256) {
    float v = src[m];
    clusters_out[m] = v;
  }
}

// compressed = attn @ clusters  (exact f32; reads only attn_out/clusters_out)
__global__ __launch_bounds__(256) void compress_kernel(
    const float* __restrict__ attn, const float* __restrict__ Cl,
    float* __restrict__ outC) {
  __shared__ float Csh[64 * 64];
  __shared__ float Ash[64 * 64];
  float4* Csh4 = (float4*)Csh;
  float4* Ash4 = (float4*)Ash;
  const int t = threadIdx.x;
  const int blk = blockIdx.x;
  const int rowBase = blk * ROWS_PB;
  const int rg = t >> 4, dg = t & 15;

  {
    const float4* gC = (const float4*)Cl;
#pragma unroll
    for (int q = 0; q < 4; ++q) {
      int m = t + 256 * q;
      Csh4[m ^ ((m >> 6) & 15)] = gC[m];
    }
  }

  for (int tile = 0; tile < 4; ++tile) {
    __syncthreads();
    {
      const float4* gA = (const float4*)(attn + (size_t)(rowBase + tile * 64) * KC);
#pragma unroll
      for (int q = 0; q < 4; ++q) {
        int m = t + 256 * q;
        Ash4[m ^ ((m >> 6) & 15)] = gA[m];
      }
    }
    __syncthreads();
    float acc[4][4] = {{0.f}};
#pragma unroll 4
    for (int c = 0; c < 16; ++c) {
      float4 av[4], cv[4];
#pragma unroll
      for (int i = 0; i < 4; ++i) av[i] = Ash4[((rg * 4 + i) * 16 + c) ^ rg];
#pragma unroll
      for (int j = 0; j < 4; ++j) cv[j] = Csh4[((c * 4 + j) * 16 + dg) ^ c];
#pragma unroll
      for (int i = 0; i < 4; ++i) {
        float a0 = fmaf(av[i].x, cv[0].x, acc[i][0]);
        a0 = fmaf(av[i].y, cv[1].x, a0);
        a0 = fmaf(av[i].z, cv[2].x, a0);
        acc[i][0] = fmaf(av[i].w, cv[3].x, a0);
        float a1 = fmaf(av[i].x, cv[0].y, acc[i][1]);
        a1 = fmaf(av[i].y, cv[1].y, a1);
        a1 = fmaf(av[i].z, cv[2].y, a1);
        acc[i][1] = fmaf(av[i].w, cv[3].y, a1);
        float a2 = fmaf(av[i].x, cv[0].z, acc[i][2]);
        a2 = fmaf(av[i].y, cv[1].z, a2);
        a2 = fmaf(av[i].z, cv[2].z, a2);
        acc[i][2] = fmaf(av[i].w, cv[3].z, a2);
        float a3 = fmaf(av[i].x, cv[0].w, acc[i][3]);
        a3 = fmaf(av[i].y, cv[1].w, a3);
        a3 = fmaf(av[i].z, cv[2].w, a3);
        acc[i][3] = fmaf(av[i].w, cv[3].w, a3);
      }
    }
    float4* gO = (float4*)(outC + (size_t)(rowBase + tile * 64) * DIM);
#pragma unroll
    for (int i = 0; i < 4; ++i)
      gO[(rg * 4 + i) * 16 + dg] = make_float4(acc[i][0], acc[i][1], acc[i][2], acc[i][3]);
  }
}

extern "C" void kernel_launch(void* const* d_in, const int* in_sizes, int n_in,
                              void* d_out, int out_size, void* d_ws, size_t ws_size,
                              hipStream_t stream) {
  (void)in_sizes; (void)n_in; (void)d_ws; (void)ws_size; (void)out_size;
  const float* W = (const float*)d_in[0];
  const float* Cinit = (const float*)d_in[1];
  float* ob = (float*)d_out;

  float* compressed = ob;                                  // [N, D]
  float* clusters_out = ob + (size_t)N_ROWS * DIM;         // [K, D]
  float* attn_out = ob + (size_t)N_ROWS * DIM + KC * DIM;  // [N, K]

  unsigned short* WT = (unsigned short*)d_out;             // 16MB at byte 0
  float* partial = ob + PARTIAL_OFF;
  float* sumAp = ob + SUMA_OFF;
  float* newC = ob + NEWC_OFF;
  float* cur = clusters_out;                               // 16KB exact
  double* normpart = (double*)((char*)d_out + NORM_BYTE_OFF);

  prep_kernel<<<NBLK, 256, 0, stream>>>(W, WT);

  for (int it = 0; it < 10; ++it) {
    dkm_iter<<<NBLK, 512, 0, stream>>>(W, WT, Cinit, newC, cur, normpart,
                                       partial, sumAp, attn_out,
                                       (it > 0) ? 1 : 0, (it == 9) ? 1 : 0);
    reduce_kernel<<<128, 256, 0, stream>>>(partial, sumAp, cur, newC, normpart);
  }
  finalize_kernel<<<1, 256, 0, stream>>>(normpart, newC, cur, clusters_out);
  compress_kernel<<<NBLK, 256, 0, stream>>>(attn_out, clusters_out, compressed);
}

// Round 8
// 455.370 us; speedup vs baseline: 1.0005x; 1.0005x over previous
//
#include <hip/hip_runtime.h>
#include <math.h>
#include <stdint.h>

#define N_ROWS 131072
#define DIM 64
#define KC 64
#define NBLK 512
#define ROWS_PB 256

typedef __attribute__((ext_vector_type(8))) short short8;
typedef __attribute__((ext_vector_type(8))) unsigned short ushort8;
typedef __attribute__((ext_vector_type(16))) float float16;
typedef __attribute__((ext_vector_type(4))) unsigned int uint4v;
typedef __attribute__((ext_vector_type(2))) unsigned long long ulong2v;

// scratch layout (float offsets into d_out's compressed region [0, 8388608)):
// WT bf16 [64][131072] = 16MB at byte 0; partial [512][64][64] f32 = 8MB;
// suma [512][64]; newC [64][64]; normpart 128 doubles.
// cur lives in the clusters_out region (ob + 8388608, 16KB exact).
// attn region untouched until iter 9; compress overwrites compressed last.
#define PARTIAL_OFF 4194304u
#define SUMA_OFF    6291456u
#define NEWC_OFF    6324224u
#define NORM_BYTE_OFF (6328320ull * 4ull)

// round-to-nearest-even bf16 (unbiased; truncation's random error is ~2x
// larger AND biased -> measured 7e-4 cluster error in r3/r5; RNE passes)
__device__ __forceinline__ uint32_t rne16(float a) {
  uint32_t u = __float_as_uint(a);
  return (u + 0x7fffu + ((u >> 16) & 1u)) >> 16;
}

__device__ __forceinline__ uint32_t pack_bf16(float a, float b) {
  return rne16(a) | (rne16(b) << 16);
}

// RNE split: x = hi + lo + eps, |lo| <= 2^-9|x|, |eps| <= 2^-17|x|, unbiased
__device__ __forceinline__ void split2(float a, float b, uint32_t& hi, uint32_t& lo) {
  uint32_t ha = rne16(a), hb = rne16(b);
  hi = ha | (hb << 16);
  float la = a - __uint_as_float(ha << 16);
  float lb = b - __uint_as_float(hb << 16);
  lo = pack_bf16(la, lb);
}

// prep: WT[d][n] = bf16_rne(W[n][d]) (transposed copy for phase-2 B-frags)
__global__ __launch_bounds__(256) void prep_kernel(const float* __restrict__ W,
                                                   unsigned short* __restrict__ WT) {
  __shared__ unsigned short Tsh[64][256];
  const int t = threadIdx.x;
  const int blk = blockIdx.x;
  const int r = blk * 256 + t;
  const float4* p = (const float4*)(W + (size_t)r * DIM);
#pragma unroll
  for (int c = 0; c < 16; ++c) {
    float4 v = p[c];
    Tsh[c * 4 + 0][t] = (unsigned short)rne16(v.x);
    Tsh[c * 4 + 1][t] = (unsigned short)rne16(v.y);
    Tsh[c * 4 + 2][t] = (unsigned short)rne16(v.z);
    Tsh[c * 4 + 3][t] = (unsigned short)rne16(v.w);
  }
  __syncthreads();
#pragma unroll
  for (int it = 0; it < 8; ++it) {
    const int idx = it * 256 + t;
    const int d = idx >> 5, c8 = (idx & 31) * 8;
    ushort8 v = *(const ushort8*)&Tsh[d][c8];
    *(ushort8*)(WT + (size_t)d * N_ROWS + blk * 256 + c8) = v;
  }
}

// One k-means iteration. 512 blocks x 512 threads (8 waves).
// launch_bounds(512,3): reg cap ~170/wave. (512,4) capped at 128 and the
// compiler spilled ~60 regs/thread to scratch -> 58-76MB of HBM writeback
// per dispatch (r6/r7 counters). True peak need is ~110-150.
// Phase 1 (swapped): dot = mfma(A=clusters, B=W-rows), load/split/MFMA fused
// per ko-chunk; register softmax with a single shfl_xor(32) for max/sum.
// Phase 2: U = attnT @ W via mfma(attnT-frag, WT-frag loaded inline); 8 waves
// = 4 output quadrants x 2 k-row halves, combined through LDS.
__global__ __launch_bounds__(512, 3) void dkm_iter(
    const float* __restrict__ W, const unsigned short* __restrict__ WT,
    const float* __restrict__ Cinit,
    const float* __restrict__ newC, float* __restrict__ cur,
    const double* __restrict__ normpart,
    float* __restrict__ partial, float* __restrict__ sumA,
    float* __restrict__ attn_out, int useSel, int writeAttn)
{
  __shared__ __align__(16) short CbfHi[64][68];   // clusters hi bf16 (pad 68)
  __shared__ __align__(16) short CbfLo[64][68];   // clusters lo bf16
  __shared__ __align__(16) short attnT[64][264];  // attn^T bf16 [cl][row], pad
  __shared__ float csqL[64];
  __shared__ float red[512];
  __shared__ int s_cond;

  const int t = threadIdx.x;
  const int blk = blockIdx.x;
  const int wid = t >> 6, lane = t & 63, l31 = lane & 31, lh = lane >> 5;
  const int half = wid >> 2, quad = wid & 3, mg = quad >> 1, ng = quad & 1;
  const int rowBase = blk * ROWS_PB;
  const int myrow = rowBase + wid * 32 + l31;

  // ---- previous-iteration convergence gate (wave 0) ----
  if (wid == 0) {
    double v = useSel ? (normpart[lane] + normpart[64 + lane]) : 0.0;
    v += __shfl_xor(v, 1); v += __shfl_xor(v, 2); v += __shfl_xor(v, 4);
    v += __shfl_xor(v, 8); v += __shfl_xor(v, 16); v += __shfl_xor(v, 32);
    if (lane == 0) s_cond = (v > 1.0e-8) ? 1 : 0;  // ||.||_F > 1e-4
  }
  __syncthreads();  // s_cond ready

  const float* src = useSel ? (s_cond ? newC : cur) : Cinit;

  // ---- stage clusters (RNE split hi/lo), csq via 8-lane shfl, cur write ----
  {
    const int crow = t >> 3, cc = (t & 7) * 8;
    float4 c0 = *(const float4*)(src + crow * 64 + cc);
    float4 c1 = *(const float4*)(src + crow * 64 + cc + 4);
    if (blk == 0) {  // single-block cur update (idempotent when src==cur)
      *(float4*)(cur + crow * 64 + cc) = c0;
      *(float4*)(cur + crow * 64 + cc + 4) = c1;
    }
    uint32_t h0, h1, h2, h3, l0, l1, l2, l3;
    split2(c0.x, c0.y, h0, l0); split2(c0.z, c0.w, h1, l1);
    split2(c1.x, c1.y, h2, l2); split2(c1.z, c1.w, h3, l3);
    uint32_t* ph = (uint32_t*)&CbfHi[crow][cc];
    ph[0] = h0; ph[1] = h1; ph[2] = h2; ph[3] = h3;
    uint32_t* pl = (uint32_t*)&CbfLo[crow][cc];
    pl[0] = l0; pl[1] = l1; pl[2] = l2; pl[3] = l3;
    float sq = c0.x*c0.x + c0.y*c0.y + c0.z*c0.z + c0.w*c0.w
             + c1.x*c1.x + c1.y*c1.y + c1.z*c1.z + c1.w*c1.w;
    sq += __shfl_xor(sq, 1); sq += __shfl_xor(sq, 2); sq += __shfl_xor(sq, 4);
    if ((t & 7) == 0) csqL[crow] = sq;
  }
  __syncthreads();  // CbfHi/CbfLo + csqL ready

  // ---- phase 1: dot = mfma(C, Wrow), fused load+split+MFMA per k-chunk ----
  float16 dot0 = {0,0,0,0, 0,0,0,0, 0,0,0,0, 0,0,0,0};
  float16 dot1 = {0,0,0,0, 0,0,0,0, 0,0,0,0, 0,0,0,0};
  float w2 = 0.f;
  const float* pw = W + (size_t)myrow * 64 + lh * 8;
#pragma unroll
  for (int ko = 0; ko < 4; ++ko) {
    float4 a = *(const float4*)(pw + ko * 16);
    float4 b = *(const float4*)(pw + ko * 16 + 4);
    w2 += a.x*a.x + a.y*a.y + a.z*a.z + a.w*a.w
        + b.x*b.x + b.y*b.y + b.z*b.z + b.w*b.w;
    uint32_t h0, h1, h2, h3, l0, l1, l2, l3;
    split2(a.x, a.y, h0, l0); split2(a.z, a.w, h1, l1);
    split2(b.x, b.y, h2, l2); split2(b.z, b.w, h3, l3);
    uint4v th = {h0, h1, h2, h3};
    uint4v tl = {l0, l1, l2, l3};
    short8 wHi = __builtin_bit_cast(short8, th);
    short8 wLo = __builtin_bit_cast(short8, tl);
#pragma unroll
    for (int nt = 0; nt < 2; ++nt) {
      const unsigned long long* ph = (const unsigned long long*)&CbfHi[nt * 32 + l31][ko * 16 + lh * 8];
      const unsigned long long* pl = (const unsigned long long*)&CbfLo[nt * 32 + l31][ko * 16 + lh * 8];
      ulong2v vh = {ph[0], ph[1]};
      ulong2v vl = {pl[0], pl[1]};
      short8 cHi = __builtin_bit_cast(short8, vh);
      short8 cLo = __builtin_bit_cast(short8, vl);
      float16& dd = nt ? dot1 : dot0;
      dd = __builtin_amdgcn_mfma_f32_32x32x16_bf16(cHi, wHi, dd, 0, 0, 0);
      dd = __builtin_amdgcn_mfma_f32_32x32x16_bf16(cLo, wHi, dd, 0, 0, 0);
      dd = __builtin_amdgcn_mfma_f32_32x32x16_bf16(cHi, wLo, dd, 0, 0, 0);
    }
  }
  w2 += __shfl_xor(w2, 32);

  // ---- register softmax (row l31; lane^32 holds complementary clusters) ----
  float mx = -3.4e38f;
#pragma unroll
  for (int j = 0; j < 16; ++j) {
    const int cl = (j & 3) + 8 * (j >> 2) + 4 * lh;
    float d20 = fmaxf(fmaf(-2.f, dot0[j], w2 + csqL[cl]), 0.f);
    float d21 = fmaxf(fmaf(-2.f, dot1[j], w2 + csqL[cl + 32]), 0.f);
    float g0 = -sqrtf(d20), g1 = -sqrtf(d21);
    dot0[j] = g0; dot1[j] = g1;
    mx = fmaxf(mx, fmaxf(g0, g1));
  }
  mx = fmaxf(mx, __shfl_xor(mx, 32));
  float s = 0.f;
#pragma unroll
  for (int j = 0; j < 16; ++j) {
    float e0 = __expf(dot0[j] - mx), e1 = __expf(dot1[j] - mx);
    dot0[j] = e0; dot1[j] = e1;
    s += e0 + e1;
  }
  s += __shfl_xor(s, 32);
  float inv = __builtin_amdgcn_rcpf(s);

  // ---- attn out (iter 9) + pack attnT bf16 RNE for phase2 A-frags ----
  const int colA = wid * 32 + l31;
#pragma unroll
  for (int j = 0; j < 16; ++j) {
    const int cl = (j & 3) + 8 * (j >> 2) + 4 * lh;
    float a0 = dot0[j] * inv, a1 = dot1[j] * inv;
    if (writeAttn) {
      attn_out[(size_t)myrow * 64 + cl] = a0;
      attn_out[(size_t)myrow * 64 + cl + 32] = a1;
    }
    attnT[cl][colA] = (short)rne16(a0);
    attnT[cl + 32][colA] = (short)rne16(a1);
  }
  __syncthreads();  // attnT complete (dot0/dot1 dead from here)

  // ---- phase 2: U-quadrant (mg,ng), k-row half `half`; B-frags inline ----
  float16 Uacc = {0,0,0,0, 0,0,0,0, 0,0,0,0, 0,0,0,0};
  const int arow = mg * 32 + l31;
  const unsigned short* pwt =
      WT + (size_t)(ng * 32 + l31) * N_ROWS + rowBase + half * 128 + lh * 8;
#pragma unroll
  for (int c2 = 0; c2 < 4; ++c2) {
#pragma unroll
    for (int kc = 0; kc < 2; ++kc) {
      const unsigned long long* pa =
          (const unsigned long long*)&attnT[arow][half * 128 + c2 * 32 + kc * 16 + lh * 8];
      ulong2v va = {pa[0], pa[1]};
      short8 af = __builtin_bit_cast(short8, va);
      ushort8 wv = *(const ushort8*)(pwt + c2 * 32 + kc * 16);
      short8 bf = __builtin_bit_cast(short8, wv);
      Uacc = __builtin_amdgcn_mfma_f32_32x32x16_bf16(af, bf, Uacc, 0, 0, 0);
    }
  }

  // ---- sumA: column sums of attnT (bf16 RNE; denominator matches
  //      numerator's weights -> unbiased, noise ~1e-6 relative) ----
  {
    const int sk = t & 63, sg = t >> 6;
    float ssum = 0.f;
#pragma unroll
    for (int q2 = 0; q2 < 4; ++q2) {
      const uint32_t* pq = (const uint32_t*)&attnT[sk][sg * 32 + q2 * 8];
#pragma unroll
      for (int w = 0; w < 4; ++w) {
        uint32_t dv = pq[w];
        ssum += __uint_as_float(dv << 16) + __uint_as_float(dv & 0xffff0000u);
      }
    }
    red[t] = ssum;
  }
  __syncthreads();  // phase-2 A-reads + sumA reads done; red ready

  float* ured = (float*)&attnT[0][0];  // 16KB overlay on attnT
  if (half == 1) {
#pragma unroll
    for (int j = 0; j < 16; ++j) ured[(quad * 16 + j) * 64 + lane] = Uacc[j];
  }
  if (t < 64) {
    sumA[blk * 64 + t] = ((red[t] + red[t + 64]) + (red[t + 128] + red[t + 192])) +
                         ((red[t + 256] + red[t + 320]) + (red[t + 384] + red[t + 448]));
  }
  __syncthreads();
  if (half == 0) {
#pragma unroll
    for (int j = 0; j < 16; ++j) {
      float u = Uacc[j] + ured[(quad * 16 + j) * 64 + lane];
      const int k = mg * 32 + (j & 3) + 8 * (j >> 2) + 4 * lh;
      partial[((size_t)blk * 64 + k) * 64 + ng * 32 + l31] = u;
    }
  }
}

// Reduce 512 block partials -> newC (f64), norm partials. 128 blocks: (k, dhalf).
__global__ __launch_bounds__(256) void reduce_kernel(
    const float* __restrict__ partial, const float* __restrict__ sumAp,
    const float* __restrict__ curC, float* __restrict__ newC,
    double* __restrict__ normpart) {
  const int k = blockIdx.x >> 1, dh = blockIdx.x & 1;
  const int t = threadIdx.x;
  const int d = dh * 32 + (t & 31), q = t >> 5;
  double acc = 0.0;
  for (int b = q * 64; b < q * 64 + 64; ++b)
    acc += (double)partial[((size_t)b * 64 + k) * 64 + d];
  __shared__ double sh[256];
  __shared__ double sh2[256];
  sh[t] = acc;
  sh2[t] = (double)sumAp[t * 64 + k] + (double)sumAp[(t + 256) * 64 + k];
  __syncthreads();
  for (int s = 128; s >= 1; s >>= 1) {
    if (t < s) sh2[t] += sh2[t + s];
    __syncthreads();
  }
  if (t < 32) {
    double tot = ((sh[t] + sh[t + 32]) + (sh[t + 64] + sh[t + 96])) +
                 ((sh[t + 128] + sh[t + 160]) + (sh[t + 192] + sh[t + 224]));
    float nc = (float)(tot / sh2[0]);
    newC[k * 64 + d] = nc;
    double diff = (double)curC[k * 64 + d] - (double)nc;
    sh[t] = diff * diff;
  }
  __syncthreads();
  if (t == 0) {
    double s = 0.0;
#pragma unroll
    for (int i = 0; i < 32; ++i) s += sh[i];
    normpart[blockIdx.x] = s;
  }
}

// Final select: clusters_out = (||cur9 - new9|| > eps) ? newC : cur
// (cur aliases clusters_out; per-element read-then-write is safe)
__global__ __launch_bounds__(256) void finalize_kernel(
    const double* __restrict__ np, const float* __restrict__ newC,
    const float* __restrict__ cur, float* __restrict__ clusters_out) {
  __shared__ double sh[64];
  __shared__ int sc;
  int t = threadIdx.x;
  if (t < 64) sh[t] = np[t] + np[t + 64];
  __syncthreads();
  if (t == 0) {
    double s = 0.0;
    for (int i = 0; i < 64; ++i) s += sh[i];
    sc = (s > 1.0e-8) ? 1 : 0;
  }
  __syncthreads();
  const float* src = sc ? newC : cur;
  for (int m = t; m < 4096; m += 256) {
    float v = src[m];
    clusters_out[m] = v;
  }
}

// compressed = attn @ clusters  (exact f32; reads only attn_out/clusters_out)
__global__ __launch_bounds__(256) void compress_kernel(
    const float* __restrict__ attn, const float* __restrict__ Cl,
    float* __restrict__ outC) {
  __shared__ float Csh[64 * 64];
  __shared__ float Ash[64 * 64];
  float4* Csh4 = (float4*)Csh;
  float4* Ash4 = (float4*)Ash;
  const int t = threadIdx.x;
  const int blk = blockIdx.x;
  const int rowBase = blk * ROWS_PB;
  const int rg = t >> 4, dg = t & 15;

  {
    const float4* gC = (const float4*)Cl;
#pragma unroll
    for (int q = 0; q < 4; ++q) {
      int m = t + 256 * q;
      Csh4[m ^ ((m >> 6) & 15)] = gC[m];
    }
  }

  for (int tile = 0; tile < 4; ++tile) {
    __syncthreads();
    {
      const float4* gA = (const float4*)(attn + (size_t)(rowBase + tile * 64) * KC);
#pragma unroll
      for (int q = 0; q < 4; ++q) {
        int m = t + 256 * q;
        Ash4[m ^ ((m >> 6) & 15)] = gA[m];
      }
    }
    __syncthreads();
    float acc[4][4] = {{0.f}};
#pragma unroll 4
    for (int c = 0; c < 16; ++c) {
      float4 av[4], cv[4];
#pragma unroll
      for (int i = 0; i < 4; ++i) av[i] = Ash4[((rg * 4 + i) * 16 + c) ^ rg];
#pragma unroll
      for (int j = 0; j < 4; ++j) cv[j] = Csh4[((c * 4 + j) * 16 + dg) ^ c];
#pragma unroll
      for (int i = 0; i < 4; ++i) {
        float a0 = fmaf(av[i].x, cv[0].x, acc[i][0]);
        a0 = fmaf(av[i].y, cv[1].x, a0);
        a0 = fmaf(av[i].z, cv[2].x, a0);
        acc[i][0] = fmaf(av[i].w, cv[3].x, a0);
        float a1 = fmaf(av[i].x, cv[0].y, acc[i][1]);
        a1 = fmaf(av[i].y, cv[1].y, a1);
        a1 = fmaf(av[i].z, cv[2].y, a1);
        acc[i][1] = fmaf(av[i].w, cv[3].y, a1);
        float a2 = fmaf(av[i].x, cv[0].z, acc[i][2]);
        a2 = fmaf(av[i].y, cv[1].z, a2);
        a2 = fmaf(av[i].z, cv[2].z, a2);
        acc[i][2] = fmaf(av[i].w, cv[3].z, a2);
        float a3 = fmaf(av[i].x, cv[0].w, acc[i][3]);
        a3 = fmaf(av[i].y, cv[1].w, a3);
        a3 = fmaf(av[i].z, cv[2].w, a3);
        acc[i][3] = fmaf(av[i].w, cv[3].w, a3);
      }
    }
    float4* gO = (float4*)(outC + (size_t)(rowBase + tile * 64) * DIM);
#pragma unroll
    for (int i = 0; i < 4; ++i)
      gO[(rg * 4 + i) * 16 + dg] = make_float4(acc[i][0], acc[i][1], acc[i][2], acc[i][3]);
  }
}

extern "C" void kernel_launch(void* const* d_in, const int* in_sizes, int n_in,
                              void* d_out, int out_size, void* d_ws, size_t ws_size,
                              hipStream_t stream) {
  (void)in_sizes; (void)n_in; (void)d_ws; (void)ws_size; (void)out_size;
  const float* W = (const float*)d_in[0];
  const float* Cinit = (const float*)d_in[1];
  float* ob = (float*)d_out;

  float* compressed = ob;                                  // [N, D]
  float* clusters_out = ob + (size_t)N_ROWS * DIM;         // [K, D]
  float* attn_out = ob + (size_t)N_ROWS * DIM + KC * DIM;  // [N, K]

  unsigned short* WT = (unsigned short*)d_out;             // 16MB at byte 0
  float* partial = ob + PARTIAL_OFF;
  float* sumAp = ob + SUMA_OFF;
  float* newC = ob + NEWC_OFF;
  float* cur = clusters_out;                               // 16KB exact
  double* normpart = (double*)((char*)d_out + NORM_BYTE_OFF);

  prep_kernel<<<NBLK, 256, 0, stream>>>(W, WT);

  for (int it = 0; it < 10; ++it) {
    dkm_iter<<<NBLK, 512, 0, stream>>>(W, WT, Cinit, newC, cur, normpart,
                                       partial, sumAp, attn_out,
                                       (it > 0) ? 1 : 0, (it == 9) ? 1 : 0);
    reduce_kernel<<<128, 256, 0, stream>>>(partial, sumAp, cur, newC, normpart);
  }
  finalize_kernel<<<1, 256, 0, stream>>>(normpart, newC, cur, clusters_out);
  compress_kernel<<<NBLK, 256, 0, stream>>>(attn_out, clusters_out, compressed);
}